// Round 1
// baseline (93820.081 us; speedup 1.0000x reference)
//
#include <hip/hip_runtime.h>
#include <math.h>

#define D_MODEL 768
#define N_HEAD 12
#define D_HEAD 64
#define D_INNER 3072
#define N_LAYER 12
#define MEM_LEN 512
#define BSZ 4
#define QLEN 1024
#define KLEN (MEM_LEN + QLEN)   // 1536
#define SCALE_ATTN 0.125f
#define EMB_SCALE 27.712812921102035f

// ---------------------------------------------------------------- utilities

__device__ __forceinline__ float block_reduce_max(float v, float* red) {
    int t = threadIdx.x;
    red[t] = v; __syncthreads();
    for (int s = 128; s > 0; s >>= 1) {
        if (t < s) red[t] = fmaxf(red[t], red[t + s]);
        __syncthreads();
    }
    float r = red[0]; __syncthreads();
    return r;
}

__device__ __forceinline__ float block_reduce_sum(float v, float* red) {
    int t = threadIdx.x;
    red[t] = v; __syncthreads();
    for (int s = 128; s > 0; s >>= 1) {
        if (t < s) red[t] += red[t + s];
        __syncthreads();
    }
    float r = red[0]; __syncthreads();
    return r;
}

// ---------------------------------------------------------------- kernels

// sinusoidal relative position embedding, pos_seq = klen-1 .. 0
__global__ __launch_bounds__(256) void pos_emb_kernel(float* __restrict__ pe) {
    int j = blockIdx.x;                      // 0..KLEN-1
    float pos = (float)(KLEN - 1 - j);
    for (int e = 0; e < 3; e++) {
        int d = e * 256 + threadIdx.x;       // 0..767
        int tt = (d < 384) ? d : d - 384;
        // inv_freq[tt] = 10000^(-(2*tt)/768)
        float freq = expf(-9.210340371976184f * ((float)(2 * tt) * (1.0f / 768.0f)));
        float arg = pos * freq;
        pe[(size_t)j * 768 + d] = (d < 384) ? sinf(arg) : cosf(arg);
    }
}

// core[q,b,:] = emb_table[ids[b,q]] * EMB_SCALE     (core layout [Q,B,D])
__global__ __launch_bounds__(256) void embed_kernel(const int* __restrict__ ids,
                                                    const float* __restrict__ emb,
                                                    float* __restrict__ core) {
    int qb = blockIdx.x;                     // q*4+b
    int q = qb >> 2, b = qb & 3;
    int id = ids[b * QLEN + q];
    const float* e = emb + (size_t)id * 768;
    float* o = core + (size_t)qb * 768;
    for (int k = threadIdx.x; k < 768; k += 256) o[k] = e[k] * EMB_SCALE;
}

// builds cat = [mems[l]; core]  ([KLEN,B,D]) and writes new_mems[l] = core[512:1024]
__global__ __launch_bounds__(256) void prep_kernel(const float* __restrict__ core,
                                                   const float* __restrict__ mems,
                                                   float* __restrict__ cat,
                                                   float* __restrict__ omems,
                                                   int layer) {
    int jb = blockIdx.x;                     // j*4+b, j in [0,KLEN)
    int j = jb >> 2, b = jb & 3;
    for (int e = 0; e < 3; e++) {
        int d = e * 256 + threadIdx.x;
        float v;
        if (j < MEM_LEN)
            v = mems[(((size_t)layer * MEM_LEN + j) * 4 + b) * 768 + d];
        else
            v = core[((size_t)(j - MEM_LEN) * 4 + b) * 768 + d];
        cat[(size_t)jb * 768 + d] = v;
        if (j >= QLEN)
            omems[(((size_t)layer * MEM_LEN + (j - QLEN)) * 4 + b) * 768 + d] = v;
    }
}

// C[M,N] = A[M,K] @ B[K,N]  (+bias[n]) (+res[m,n]) (+relu)
// FLAGS: bit0 = bias, bit1 = relu, bit2 = residual
template <int FLAGS>
__global__ __launch_bounds__(256) void gemm_kernel(const float* __restrict__ A,
                                                   const float* __restrict__ B,
                                                   const float* __restrict__ bias,
                                                   const float* __restrict__ res,
                                                   float* __restrict__ C,
                                                   int M, int N, int K) {
    __shared__ float As[16][65];   // +1 pad: transpose-store without bank conflicts
    __shared__ float Bs[16][64];
    int t = threadIdx.x;
    int tx = t & 15, ty = t >> 4;
    int n0 = blockIdx.x * 64, m0 = blockIdx.y * 64;
    float acc[4][4] = {};
    for (int k0 = 0; k0 < K; k0 += 16) {
#pragma unroll
        for (int e = 0; e < 4; e++) {
            int idx = t + e * 256;
            int am = idx >> 4, ak = idx & 15;
            As[ak][am] = A[(size_t)(m0 + am) * K + k0 + ak];
            int bk = idx >> 6, bn = idx & 63;
            Bs[bk][bn] = B[(size_t)(k0 + bk) * N + n0 + bn];
        }
        __syncthreads();
#pragma unroll
        for (int kk = 0; kk < 16; kk++) {
            float a[4], b[4];
#pragma unroll
            for (int u = 0; u < 4; u++) { a[u] = As[kk][ty * 4 + u]; b[u] = Bs[kk][tx * 4 + u]; }
#pragma unroll
            for (int y = 0; y < 4; y++)
#pragma unroll
                for (int x = 0; x < 4; x++)
                    acc[y][x] = fmaf(a[y], b[x], acc[y][x]);
        }
        __syncthreads();
    }
#pragma unroll
    for (int y = 0; y < 4; y++) {
        int m = m0 + ty * 4 + y;
#pragma unroll
        for (int x = 0; x < 4; x++) {
            int n = n0 + tx * 4 + x;
            float v = acc[y][x];
            if (FLAGS & 1) v += bias[n];
            if (FLAGS & 4) v += res[(size_t)m * N + n];
            if (FLAGS & 2) v = fmaxf(v, 0.f);
            C[(size_t)m * N + n] = v;
        }
    }
}

// fused relative attention: one block per (query row i, batch b, head n)
// w_heads: [KLEN,B,2304] (q|k|v), r_heads: [KLEN,768]
// out: attn_vec [Q,B,768]
__global__ __launch_bounds__(256) void attn_kernel(const float* __restrict__ wh,
                                                   const float* __restrict__ rh,
                                                   const float* __restrict__ rwb,
                                                   const float* __restrict__ rrb,
                                                   float* __restrict__ aout) {
    __shared__ float qw[64], qr[64];
    __shared__ float sc[KLEN];
    __shared__ float red[256];
    __shared__ float oa[4][64];

    int i = blockIdx.x;                  // query row
    int b = blockIdx.y / N_HEAD;
    int n = blockIdx.y % N_HEAD;
    int t = threadIdx.x;

    if (t < 64) {
        float qv = wh[(((size_t)(MEM_LEN + i) * 4 + b)) * 2304 + n * 64 + t];
        qw[t] = qv + rwb[n * 64 + t];    // content bias (r_w_bias)
        qr[t] = qv + rrb[n * 64 + t];    // position bias (r_r_bias)
    }
    __syncthreads();

    int count = i + MEM_LEN + 1;         // unmasked keys: j in [0, count)
    int rbase = QLEN - 1 - i;            // rel_shift: BD[i,j] = raw[i, j+rbase]

    float lmax = -3.4e38f;
    for (int j = t; j < count; j += 256) {
        const float4* k4 = (const float4*)(wh + ((size_t)j * 4 + b) * 2304 + 768 + n * 64);
        const float4* r4 = (const float4*)(rh + (size_t)(j + rbase) * 768 + n * 64);
        const float4* q4 = (const float4*)qw;
        const float4* p4 = (const float4*)qr;
        float acc = 0.f;
#pragma unroll
        for (int d = 0; d < 16; d++) {
            float4 kk = k4[d], rr = r4[d], qq = q4[d], pp = p4[d];
            acc += qq.x * kk.x + qq.y * kk.y + qq.z * kk.z + qq.w * kk.w;
            acc += pp.x * rr.x + pp.y * rr.y + pp.z * rr.z + pp.w * rr.w;
        }
        acc *= SCALE_ATTN;
        sc[j] = acc;
        lmax = fmaxf(lmax, acc);
    }
    float mx = block_reduce_max(lmax, red);

    float lsum = 0.f;
    for (int j = t; j < count; j += 256) {
        float e = expf(sc[j] - mx);
        sc[j] = e;
        lsum += e;
    }
    float ssum = block_reduce_sum(lsum, red);
    float inv = 1.0f / ssum;

    int c = t >> 6, d = t & 63;
    float acc = 0.f;
    for (int j = c; j < count; j += 4)
        acc = fmaf(sc[j], wh[((size_t)j * 4 + b) * 2304 + 1536 + n * 64 + d], acc);
    oa[c][d] = acc;
    __syncthreads();
    if (c == 0) {
        float r = (oa[0][d] + oa[1][d] + oa[2][d] + oa[3][d]) * inv;
        aout[((size_t)i * 4 + b) * 768 + n * 64 + d] = r;
    }
}

// LayerNorm over last dim (768): out = (x-mean)*rsqrt(var+eps)*g + b
__global__ __launch_bounds__(256) void ln_kernel(const float* __restrict__ in,
                                                 const float* __restrict__ g,
                                                 const float* __restrict__ be,
                                                 float* __restrict__ out) {
    __shared__ float s1[256], s2[256];
    int row = blockIdx.x, t = threadIdx.x;
    const float* x = in + (size_t)row * 768;
    float v0 = x[t], v1 = x[t + 256], v2 = x[t + 512];
    s1[t] = v0 + v1 + v2;
    s2[t] = v0 * v0 + v1 * v1 + v2 * v2;
    __syncthreads();
    for (int s = 128; s > 0; s >>= 1) {
        if (t < s) { s1[t] += s1[t + s]; s2[t] += s2[t + s]; }
        __syncthreads();
    }
    float mean = s1[0] * (1.0f / 768.0f);
    float var = s2[0] * (1.0f / 768.0f) - mean * mean;
    float rs = rsqrtf(var + 1e-5f);
    float* o = out + (size_t)row * 768;
    o[t]       = (v0 - mean) * rs * g[t]       + be[t];
    o[t + 256] = (v1 - mean) * rs * g[t + 256] + be[t + 256];
    o[t + 512] = (v2 - mean) * rs * g[t + 512] + be[t + 512];
}

// final head: start/end logits. core [Q,B,768]; out[0:4096]=start[b,q], [4096:8192]=end
__global__ __launch_bounds__(64) void logits_kernel(const float* __restrict__ core,
                                                    const float* __restrict__ qa_w,
                                                    const float* __restrict__ qa_b,
                                                    float* __restrict__ out) {
    int row = blockIdx.x;                // q*4+b
    int q = row >> 2, b = row & 3;
    const float* x = core + (size_t)row * 768;
    float a0 = 0.f, a1 = 0.f;
    for (int d = threadIdx.x; d < 768; d += 64) {
        float xv = x[d];
        a0 = fmaf(xv, qa_w[2 * d], a0);
        a1 = fmaf(xv, qa_w[2 * d + 1], a1);
    }
    for (int off = 32; off > 0; off >>= 1) {
        a0 += __shfl_down(a0, off);
        a1 += __shfl_down(a1, off);
    }
    if (threadIdx.x == 0) {
        out[b * QLEN + q]        = a0 + qa_b[0];
        out[4096 + b * QLEN + q] = a1 + qa_b[1];
    }
}

// ---------------------------------------------------------------- launch

extern "C" void kernel_launch(void* const* d_in, const int* in_sizes, int n_in,
                              void* d_out, int out_size, void* d_ws, size_t ws_size,
                              hipStream_t stream) {
    const int*   input_ids = (const int*)d_in[0];
    const float* mems      = (const float*)d_in[1];
    const float* emb_table = (const float*)d_in[2];
    const float* qkv_w     = (const float*)d_in[3];
    const float* r_w       = (const float*)d_in[4];
    const float* o_w       = (const float*)d_in[5];
    const float* r_w_bias  = (const float*)d_in[6];
    const float* r_r_bias  = (const float*)d_in[7];
    const float* ln1_g     = (const float*)d_in[8];
    const float* ln1_b     = (const float*)d_in[9];
    const float* ff_w1     = (const float*)d_in[10];
    const float* ff_b1     = (const float*)d_in[11];
    const float* ff_w2     = (const float*)d_in[12];
    const float* ff_b2     = (const float*)d_in[13];
    const float* ln2_g     = (const float*)d_in[14];
    const float* ln2_b     = (const float*)d_in[15];
    const float* qa_w      = (const float*)d_in[16];
    const float* qa_b      = (const float*)d_in[17];

    float* out = (float*)d_out;
    float* out_mems = out + 2 * BSZ * QLEN;   // after start/end logits

    // workspace layout (floats)
    float* ws = (float*)d_ws;
    float* pos_emb  = ws;                        ws += (size_t)KLEN * 768;        // 1536x768
    float* core     = ws;                        ws += (size_t)QLEN * BSZ * 768;  // 4096x768
    float* cat      = ws;                        ws += (size_t)KLEN * BSZ * 768;  // 6144x768 (also tmp 4096x768)
    float* w_heads  = ws;                        ws += (size_t)KLEN * BSZ * 2304; // 6144x2304 (also ff_mid 4096x3072)
    float* r_heads  = ws;                        ws += (size_t)KLEN * 768;        // 1536x768
    float* attn_out = ws;                        ws += (size_t)QLEN * BSZ * 768;  // 4096x768
    float* tmp    = cat;
    float* ff_mid = w_heads;

    pos_emb_kernel<<<KLEN, 256, 0, stream>>>(pos_emb);
    embed_kernel<<<QLEN * BSZ, 256, 0, stream>>>(input_ids, emb_table, core);

    const int Mq = KLEN * BSZ;   // 6144
    const int Mc = QLEN * BSZ;   // 4096

    for (int l = 0; l < N_LAYER; l++) {
        prep_kernel<<<KLEN * BSZ, 256, 0, stream>>>(core, mems, cat, out_mems, l);

        // qkv: [6144,768] @ [768,2304]
        gemm_kernel<0><<<dim3(2304 / 64, Mq / 64), 256, 0, stream>>>(
            cat, qkv_w + (size_t)l * 768 * 2304, nullptr, nullptr, w_heads, Mq, 2304, 768);
        // position keys: [1536,768] @ [768,768]
        gemm_kernel<0><<<dim3(768 / 64, KLEN / 64), 256, 0, stream>>>(
            pos_emb, r_w + (size_t)l * 768 * 768, nullptr, nullptr, r_heads, KLEN, 768, 768);

        attn_kernel<<<dim3(QLEN, BSZ * N_HEAD), 256, 0, stream>>>(
            w_heads, r_heads, r_w_bias + (size_t)l * 768, r_r_bias + (size_t)l * 768, attn_out);

        // output proj + residual: tmp = attn_out @ o_w + core
        gemm_kernel<4><<<dim3(768 / 64, Mc / 64), 256, 0, stream>>>(
            attn_out, o_w + (size_t)l * 768 * 768, nullptr, core, tmp, Mc, 768, 768);
        ln_kernel<<<Mc, 256, 0, stream>>>(tmp, ln1_g + l * 768, ln1_b + l * 768, core);

        // ffn
        gemm_kernel<3><<<dim3(D_INNER / 64, Mc / 64), 256, 0, stream>>>(
            core, ff_w1 + (size_t)l * 768 * D_INNER, ff_b1 + (size_t)l * D_INNER, nullptr,
            ff_mid, Mc, D_INNER, 768);
        gemm_kernel<5><<<dim3(768 / 64, Mc / 64), 256, 0, stream>>>(
            ff_mid, ff_w2 + (size_t)l * D_INNER * 768, ff_b2 + (size_t)l * 768, core,
            tmp, Mc, 768, D_INNER);
        ln_kernel<<<Mc, 256, 0, stream>>>(tmp, ln2_g + l * 768, ln2_b + l * 768, core);
    }

    logits_kernel<<<QLEN * BSZ, 64, 0, stream>>>(core, qa_w, qa_b, out);
}

// Round 2
// 23319.620 us; speedup vs baseline: 4.0232x; 4.0232x over previous
//
#include <hip/hip_runtime.h>
#include <math.h>

#define D_MODEL 768
#define N_HEAD 12
#define D_HEAD 64
#define D_INNER 3072
#define N_LAYER 12
#define MEM_LEN 512
#define BSZ 4
#define QLEN 1024
#define KLEN (MEM_LEN + QLEN)   // 1536
#define SCALE_ATTN 0.125f
#define EMB_SCALE 27.712812921102035f

// ---------------------------------------------------------------- kernels

// sinusoidal relative position embedding, pos_seq = klen-1 .. 0
__global__ __launch_bounds__(256) void pos_emb_kernel(float* __restrict__ pe) {
    int j = blockIdx.x;                      // 0..KLEN-1
    float pos = (float)(KLEN - 1 - j);
    for (int e = 0; e < 3; e++) {
        int d = e * 256 + threadIdx.x;       // 0..767
        int tt = (d < 384) ? d : d - 384;
        float freq = expf(-9.210340371976184f * ((float)(2 * tt) * (1.0f / 768.0f)));
        float arg = pos * freq;
        pe[(size_t)j * 768 + d] = (d < 384) ? sinf(arg) : cosf(arg);
    }
}

// core[q,b,:] = emb_table[ids[b,q]] * EMB_SCALE     (core layout [Q,B,D])
__global__ __launch_bounds__(256) void embed_kernel(const int* __restrict__ ids,
                                                    const float* __restrict__ emb,
                                                    float* __restrict__ core) {
    int qb = blockIdx.x;                     // q*4+b
    int q = qb >> 2, b = qb & 3;
    int id = ids[b * QLEN + q];
    const float* e = emb + (size_t)id * 768;
    float* o = core + (size_t)qb * 768;
    for (int k = threadIdx.x; k < 768; k += 256) o[k] = e[k] * EMB_SCALE;
}

// builds cat = [mems[l]; core]  ([KLEN,B,D]) and writes new_mems[l] = core[512:1024]
__global__ __launch_bounds__(256) void prep_kernel(const float* __restrict__ core,
                                                   const float* __restrict__ mems,
                                                   float* __restrict__ cat,
                                                   float* __restrict__ omems,
                                                   int layer) {
    int jb = blockIdx.x;                     // j*4+b, j in [0,KLEN)
    int j = jb >> 2, b = jb & 3;
    for (int e = 0; e < 3; e++) {
        int d = e * 256 + threadIdx.x;
        float v;
        if (j < MEM_LEN)
            v = mems[(((size_t)layer * MEM_LEN + j) * 4 + b) * 768 + d];
        else
            v = core[((size_t)(j - MEM_LEN) * 4 + b) * 768 + d];
        cat[(size_t)jb * 768 + d] = v;
        if (j >= QLEN)
            omems[(((size_t)layer * MEM_LEN + (j - QLEN)) * 4 + b) * 768 + d] = v;
    }
}

// C[M,N] = A[M,K] @ B[K,N]  (+bias[n]) (+res[m,n]) (+relu)
// FLAGS: bit0 = bias, bit1 = relu, bit2 = residual
template <int FLAGS>
__global__ __launch_bounds__(256) void gemm_kernel(const float* __restrict__ A,
                                                   const float* __restrict__ B,
                                                   const float* __restrict__ bias,
                                                   const float* __restrict__ res,
                                                   float* __restrict__ C,
                                                   int M, int N, int K) {
    __shared__ float As[16][65];   // +1 pad: transpose-store without bank conflicts
    __shared__ float Bs[16][64];
    int t = threadIdx.x;
    int tx = t & 15, ty = t >> 4;
    int n0 = blockIdx.x * 64, m0 = blockIdx.y * 64;
    float acc[4][4] = {};
    for (int k0 = 0; k0 < K; k0 += 16) {
#pragma unroll
        for (int e = 0; e < 4; e++) {
            int idx = t + e * 256;
            int am = idx >> 4, ak = idx & 15;
            As[ak][am] = A[(size_t)(m0 + am) * K + k0 + ak];
            int bk = idx >> 6, bn = idx & 63;
            Bs[bk][bn] = B[(size_t)(k0 + bk) * N + n0 + bn];
        }
        __syncthreads();
#pragma unroll
        for (int kk = 0; kk < 16; kk++) {
            float a[4], b[4];
#pragma unroll
            for (int u = 0; u < 4; u++) { a[u] = As[kk][ty * 4 + u]; b[u] = Bs[kk][tx * 4 + u]; }
#pragma unroll
            for (int y = 0; y < 4; y++)
#pragma unroll
                for (int x = 0; x < 4; x++)
                    acc[y][x] = fmaf(a[y], b[x], acc[y][x]);
        }
        __syncthreads();
    }
#pragma unroll
    for (int y = 0; y < 4; y++) {
        int m = m0 + ty * 4 + y;
#pragma unroll
        for (int x = 0; x < 4; x++) {
            int n = n0 + tx * 4 + x;
            float v = acc[y][x];
            if (FLAGS & 1) v += bias[n];
            if (FLAGS & 4) v += res[(size_t)m * N + n];
            if (FLAGS & 2) v = fmaxf(v, 0.f);
            C[(size_t)m * N + n] = v;
        }
    }
}

// ---------------------------------------------------------------- flash attention
// one block per (64-row q tile, b, head). 256 threads, 4x4 register tiles.
// score[i][j] = (q_i+rwb).k_j + (q_i+rrb).r[j-i+QLEN-1], masked j-i>MEM_LEN,
// online softmax, PV accumulated in registers.
__global__ __launch_bounds__(256) void attn_flash_kernel(const float* __restrict__ wh,
                                                         const float* __restrict__ rh,
                                                         const float* __restrict__ rwb,
                                                         const float* __restrict__ rrb,
                                                         float* __restrict__ aout) {
    __shared__ float Qw[64][65];     // q + r_w_bias, row-major [i][kk]
    __shared__ float db_s[64];       // rrb - rwb per dim
    __shared__ float buf[8256];      // union: Ks[64][65] | Rs[127][65] | Vs[64][64]+Ps[64][65]
    float (*Ks)[65] = (float (*)[65])buf;
    float (*Rs)[65] = (float (*)[65])buf;
    float (*Vs)[64] = (float (*)[64])buf;
    float (*Ps)[65] = (float (*)[65])(buf + 4096);

    int qt = blockIdx.x;
    int i0 = qt * 64;
    int b = blockIdx.y / N_HEAD;
    int n = blockIdx.y % N_HEAD;
    int t = threadIdx.x;
    int tx = t & 15, ty = t >> 4;

    // stage Q tile (+content bias) and bias delta
#pragma unroll
    for (int rep = 0; rep < 4; rep++) {
        int r = rep * 16 + (t >> 4);
        int c = (t & 15) * 4;
        float4 qv = *(const float4*)&wh[((size_t)(MEM_LEN + i0 + r) * 4 + b) * 2304 + n * 64 + c];
        float4 bw = *(const float4*)&rwb[n * 64 + c];
        Qw[r][c + 0] = qv.x + bw.x;
        Qw[r][c + 1] = qv.y + bw.y;
        Qw[r][c + 2] = qv.z + bw.z;
        Qw[r][c + 3] = qv.w + bw.w;
    }
    if (t < 64) db_s[t] = rrb[n * 64 + t] - rwb[n * 64 + t];

    float m_r[4], l_r[4], o_r[4][4];
#pragma unroll
    for (int y = 0; y < 4; y++) {
        m_r[y] = -1e30f; l_r[y] = 0.f;
#pragma unroll
        for (int x = 0; x < 4; x++) o_r[y][x] = 0.f;
    }

    int ntile = qt + 9;   // j tiles cover [0, i0+63+512]
    for (int jt = 0; jt < ntile; jt++) {
        int j0 = jt * 64;
        __syncthreads();   // prev PV / initial Qw staging complete
        // ---- stage K tile [j][kk]
#pragma unroll
        for (int rep = 0; rep < 4; rep++) {
            int r = rep * 16 + (t >> 4);
            int c = (t & 15) * 4;
            float4 v = *(const float4*)&wh[((size_t)(j0 + r) * 4 + b) * 2304 + 768 + n * 64 + c];
            Ks[r][c + 0] = v.x; Ks[r][c + 1] = v.y; Ks[r][c + 2] = v.z; Ks[r][c + 3] = v.w;
        }
        __syncthreads();
        // ---- phase A: AC term
        float p[4][4] = {};
        for (int kk = 0; kk < 64; kk++) {
            float av[4], bv[4];
#pragma unroll
            for (int y = 0; y < 4; y++) av[y] = Qw[ty * 4 + y][kk];
#pragma unroll
            for (int x = 0; x < 4; x++) bv[x] = Ks[tx * 4 + x][kk];
#pragma unroll
            for (int y = 0; y < 4; y++)
#pragma unroll
                for (int x = 0; x < 4; x++)
                    p[y][x] = fmaf(av[y], bv[x], p[y][x]);
        }
        __syncthreads();   // done with Ks
        // ---- stage R strip: rows g = rbase + s, s in [0,127)
        int rbase = j0 - i0 + 960;
        for (int s = (t >> 4); s < 127; s += 16) {
            int g = rbase + s; if (g > KLEN - 1) g = KLEN - 1;   // clamped rows are masked-only
            int c = (t & 15) * 4;
            float4 v = *(const float4*)&rh[(size_t)g * 768 + n * 64 + c];
            Rs[s][c + 0] = v.x; Rs[s][c + 1] = v.y; Rs[s][c + 2] = v.z; Rs[s][c + 3] = v.w;
        }
        __syncthreads();
        // ---- phase B: BD term. strip idx = 63 + (j-j0) - (i-i0) = 63+4(tx-ty)+(x-y)
        {
            int sb = 60 + 4 * (tx - ty);   // + (3 + x - y) in [0,6]
            for (int kk = 0; kk < 64; kk++) {
                float dbk = db_s[kk];
                float av[4], r7[7];
#pragma unroll
                for (int y = 0; y < 4; y++) av[y] = Qw[ty * 4 + y][kk] + dbk;
#pragma unroll
                for (int u = 0; u < 7; u++) r7[u] = Rs[sb + u][kk];
#pragma unroll
                for (int y = 0; y < 4; y++)
#pragma unroll
                    for (int x = 0; x < 4; x++)
                        p[y][x] = fmaf(av[y], r7[3 + x - y], p[y][x]);
            }
        }
        // ---- scale + mask + online softmax (registers + 16-lane shuffles)
        float pm[4], rs[4];
#pragma unroll
        for (int y = 0; y < 4; y++) {
            int ig = i0 + ty * 4 + y;
            float mx = -1e30f;
#pragma unroll
            for (int x = 0; x < 4; x++) {
                int jg = j0 + tx * 4 + x;
                float sc = (jg - ig <= MEM_LEN) ? p[y][x] * SCALE_ATTN : -1e30f;
                p[y][x] = sc;
                mx = fmaxf(mx, sc);
            }
            pm[y] = mx;
        }
#pragma unroll
        for (int off = 1; off < 16; off <<= 1)
#pragma unroll
            for (int y = 0; y < 4; y++) pm[y] = fmaxf(pm[y], __shfl_xor(pm[y], off));
#pragma unroll
        for (int y = 0; y < 4; y++) {
            float nm = fmaxf(m_r[y], pm[y]);
            float al = __expf(m_r[y] - nm);
            m_r[y] = nm;
            float sum = 0.f;
#pragma unroll
            for (int x = 0; x < 4; x++) {
                float e = __expf(p[y][x] - nm);
                p[y][x] = e;
                sum += e;
            }
            rs[y] = sum;
            l_r[y] *= al;
#pragma unroll
            for (int x = 0; x < 4; x++) o_r[y][x] *= al;
        }
#pragma unroll
        for (int off = 1; off < 16; off <<= 1)
#pragma unroll
            for (int y = 0; y < 4; y++) rs[y] += __shfl_xor(rs[y], off);
#pragma unroll
        for (int y = 0; y < 4; y++) l_r[y] += rs[y];
        __syncthreads();   // done with Rs
        // ---- stage V tile + P transpose
#pragma unroll
        for (int y = 0; y < 4; y++)
#pragma unroll
            for (int x = 0; x < 4; x++)
                Ps[tx * 4 + x][ty * 4 + y] = p[y][x];
#pragma unroll
        for (int rep = 0; rep < 4; rep++) {
            int r = rep * 16 + (t >> 4);
            int c = (t & 15) * 4;
            *(float4*)&Vs[r][c] =
                *(const float4*)&wh[((size_t)(j0 + r) * 4 + b) * 2304 + 1536 + n * 64 + c];
        }
        __syncthreads();
        // ---- PV
        for (int j = 0; j < 64; j++) {
            float a4[4], b4[4];
#pragma unroll
            for (int y = 0; y < 4; y++) a4[y] = Ps[j][ty * 4 + y];
#pragma unroll
            for (int x = 0; x < 4; x++) b4[x] = Vs[j][tx * 4 + x];
#pragma unroll
            for (int y = 0; y < 4; y++)
#pragma unroll
                for (int x = 0; x < 4; x++)
                    o_r[y][x] = fmaf(a4[y], b4[x], o_r[y][x]);
        }
    }
    // ---- epilogue
#pragma unroll
    for (int y = 0; y < 4; y++) {
        float inv = 1.0f / l_r[y];
        int ig = i0 + ty * 4 + y;
        float4 ov = { o_r[y][0] * inv, o_r[y][1] * inv, o_r[y][2] * inv, o_r[y][3] * inv };
        *(float4*)&aout[((size_t)ig * 4 + b) * 768 + n * 64 + tx * 4] = ov;
    }
}

// LayerNorm over last dim (768): out = (x-mean)*rsqrt(var+eps)*g + b
__global__ __launch_bounds__(256) void ln_kernel(const float* __restrict__ in,
                                                 const float* __restrict__ g,
                                                 const float* __restrict__ be,
                                                 float* __restrict__ out) {
    __shared__ float s1[256], s2[256];
    int row = blockIdx.x, t = threadIdx.x;
    const float* x = in + (size_t)row * 768;
    float v0 = x[t], v1 = x[t + 256], v2 = x[t + 512];
    s1[t] = v0 + v1 + v2;
    s2[t] = v0 * v0 + v1 * v1 + v2 * v2;
    __syncthreads();
    for (int s = 128; s > 0; s >>= 1) {
        if (t < s) { s1[t] += s1[t + s]; s2[t] += s2[t + s]; }
        __syncthreads();
    }
    float mean = s1[0] * (1.0f / 768.0f);
    float var = s2[0] * (1.0f / 768.0f) - mean * mean;
    float rs = rsqrtf(var + 1e-5f);
    float* o = out + (size_t)row * 768;
    o[t]       = (v0 - mean) * rs * g[t]       + be[t];
    o[t + 256] = (v1 - mean) * rs * g[t + 256] + be[t + 256];
    o[t + 512] = (v2 - mean) * rs * g[t + 512] + be[t + 512];
}

// final head: start/end logits. core [Q,B,768]; out[0:4096]=start[b,q], [4096:8192]=end
__global__ __launch_bounds__(64) void logits_kernel(const float* __restrict__ core,
                                                    const float* __restrict__ qa_w,
                                                    const float* __restrict__ qa_b,
                                                    float* __restrict__ out) {
    int row = blockIdx.x;                // q*4+b
    int q = row >> 2, b = row & 3;
    const float* x = core + (size_t)row * 768;
    float a0 = 0.f, a1 = 0.f;
    for (int d = threadIdx.x; d < 768; d += 64) {
        float xv = x[d];
        a0 = fmaf(xv, qa_w[2 * d], a0);
        a1 = fmaf(xv, qa_w[2 * d + 1], a1);
    }
    for (int off = 32; off > 0; off >>= 1) {
        a0 += __shfl_down(a0, off);
        a1 += __shfl_down(a1, off);
    }
    if (threadIdx.x == 0) {
        out[b * QLEN + q]        = a0 + qa_b[0];
        out[4096 + b * QLEN + q] = a1 + qa_b[1];
    }
}

// ---------------------------------------------------------------- launch

extern "C" void kernel_launch(void* const* d_in, const int* in_sizes, int n_in,
                              void* d_out, int out_size, void* d_ws, size_t ws_size,
                              hipStream_t stream) {
    const int*   input_ids = (const int*)d_in[0];
    const float* mems      = (const float*)d_in[1];
    const float* emb_table = (const float*)d_in[2];
    const float* qkv_w     = (const float*)d_in[3];
    const float* r_w       = (const float*)d_in[4];
    const float* o_w       = (const float*)d_in[5];
    const float* r_w_bias  = (const float*)d_in[6];
    const float* r_r_bias  = (const float*)d_in[7];
    const float* ln1_g     = (const float*)d_in[8];
    const float* ln1_b     = (const float*)d_in[9];
    const float* ff_w1     = (const float*)d_in[10];
    const float* ff_b1     = (const float*)d_in[11];
    const float* ff_w2     = (const float*)d_in[12];
    const float* ff_b2     = (const float*)d_in[13];
    const float* ln2_g     = (const float*)d_in[14];
    const float* ln2_b     = (const float*)d_in[15];
    const float* qa_w      = (const float*)d_in[16];
    const float* qa_b      = (const float*)d_in[17];

    float* out = (float*)d_out;
    float* out_mems = out + 2 * BSZ * QLEN;   // after start/end logits

    // workspace layout (floats)
    float* ws = (float*)d_ws;
    float* pos_emb  = ws;                        ws += (size_t)KLEN * 768;        // 1536x768
    float* core     = ws;                        ws += (size_t)QLEN * BSZ * 768;  // 4096x768
    float* cat      = ws;                        ws += (size_t)KLEN * BSZ * 768;  // 6144x768 (also tmp 4096x768)
    float* w_heads  = ws;                        ws += (size_t)KLEN * BSZ * 2304; // 6144x2304 (also ff_mid 4096x3072)
    float* r_heads  = ws;                        ws += (size_t)KLEN * 768;        // 1536x768
    float* attn_out = ws;                        ws += (size_t)QLEN * BSZ * 768;  // 4096x768
    float* tmp    = cat;
    float* ff_mid = w_heads;

    pos_emb_kernel<<<KLEN, 256, 0, stream>>>(pos_emb);
    embed_kernel<<<QLEN * BSZ, 256, 0, stream>>>(input_ids, emb_table, core);

    const int Mq = KLEN * BSZ;   // 6144
    const int Mc = QLEN * BSZ;   // 4096

    for (int l = 0; l < N_LAYER; l++) {
        prep_kernel<<<KLEN * BSZ, 256, 0, stream>>>(core, mems, cat, out_mems, l);

        // qkv: [6144,768] @ [768,2304]
        gemm_kernel<0><<<dim3(2304 / 64, Mq / 64), 256, 0, stream>>>(
            cat, qkv_w + (size_t)l * 768 * 2304, nullptr, nullptr, w_heads, Mq, 2304, 768);
        // position keys: [1536,768] @ [768,768]
        gemm_kernel<0><<<dim3(768 / 64, KLEN / 64), 256, 0, stream>>>(
            pos_emb, r_w + (size_t)l * 768 * 768, nullptr, nullptr, r_heads, KLEN, 768, 768);

        attn_flash_kernel<<<dim3(QLEN / 64, BSZ * N_HEAD), 256, 0, stream>>>(
            w_heads, r_heads, r_w_bias + (size_t)l * 768, r_r_bias + (size_t)l * 768, attn_out);

        // output proj + residual: tmp = attn_out @ o_w + core
        gemm_kernel<4><<<dim3(768 / 64, Mc / 64), 256, 0, stream>>>(
            attn_out, o_w + (size_t)l * 768 * 768, nullptr, core, tmp, Mc, 768, 768);
        ln_kernel<<<Mc, 256, 0, stream>>>(tmp, ln1_g + l * 768, ln1_b + l * 768, core);

        // ffn
        gemm_kernel<3><<<dim3(D_INNER / 64, Mc / 64), 256, 0, stream>>>(
            core, ff_w1 + (size_t)l * 768 * D_INNER, ff_b1 + (size_t)l * D_INNER, nullptr,
            ff_mid, Mc, D_INNER, 768);
        gemm_kernel<5><<<dim3(768 / 64, Mc / 64), 256, 0, stream>>>(
            ff_mid, ff_w2 + (size_t)l * D_INNER * 768, ff_b2 + (size_t)l * 768, core,
            tmp, Mc, 768, D_INNER);
        ln_kernel<<<Mc, 256, 0, stream>>>(tmp, ln2_g + l * 768, ln2_b + l * 768, core);
    }

    logits_kernel<<<QLEN * BSZ, 64, 0, stream>>>(core, qa_w, qa_b, out);
}